// Round 2
// baseline (80.151 us; speedup 1.0000x reference)
//
#include <hip/hip_runtime.h>

#define BB 8
#define NN 256
#define DD 128
#define SW 257  // W_msg row stride (2D+1)
#define SU 256  // W_upd row stride (2D)
#define EPSV 1e-5f

__device__ __forceinline__ float wave_reduce_add(float v) {
#pragma unroll
  for (int off = 32; off > 0; off >>= 1) v += __shfl_xor(v, off, 64);
  return v;
}

// ---------------- K0: transpose W_msg[:, :256] and W_upd into [d][e] -------
__global__ __launch_bounds__(512) void k_wt(const float* __restrict__ Wm,
                                            const float* __restrict__ Wu,
                                            float* __restrict__ WmT,
                                            float* __restrict__ WuT) {
  const int idx = blockIdx.x * 512 + threadIdx.x;  // 65536
  const int half = idx >> 15;
  const int r = idx & 32767;
  const int d = r >> 7, e = r & 127;
  if (half == 0) WmT[r] = Wm[e * SW + d];
  else           WuT[r] = Wu[e * SU + d];
}

// ---------------- K1: centered u,s + per-row LN scalars --------------------
// 256 threads: half 0 -> u (Wt), half 1 -> s (Ws). 4 rows/block.
__global__ __launch_bounds__(256) void k_proj(
    const float* __restrict__ h, const float* __restrict__ WmT,
    const float* __restrict__ Wm, const float* __restrict__ bmsg,
    float* __restrict__ u, float* __restrict__ s,
    float* __restrict__ rowA, float* __restrict__ rowB,
    float* __restrict__ rowD2, float* __restrict__ rowE2) {
  const int blk = blockIdx.x;            // 512: 64 per batch, 4 rows each
  const int b = blk >> 6;
  const int r0 = (blk & 63) * 4;
  const int tid = threadIdx.x;
  const int half = tid >> 7;
  const int e = tid & 127;
  const int wv = tid >> 6, lane = tid & 63;

  __shared__ float hs[4][DD];
  __shared__ float pS[4][4], pw[4], pQ[4][4], pD[4][4];

  const float* hb = h + (size_t)(b * NN + r0) * DD;
  if (tid < DD) {
#pragma unroll
    for (int r = 0; r < 4; ++r) hs[r][e] = hb[r * DD + e];
  }
  __syncthreads();

  float acc[4];
  const float bm = (half == 0) ? bmsg[e] : 0.f;   // fold b_msg into u
#pragma unroll
  for (int r = 0; r < 4; ++r) acc[r] = bm;

  const float* wt = WmT + (size_t)half * DD * DD + e;   // [k][e], coalesced
  for (int k = 0; k < DD; k += 4) {
    const float w0 = wt[(k + 0) * DD], w1 = wt[(k + 1) * DD];
    const float w2 = wt[(k + 2) * DD], w3 = wt[(k + 3) * DD];
#pragma unroll
    for (int r = 0; r < 4; ++r) {
      const float4 hv = *(const float4*)(&hs[r][k]);
      acc[r] = fmaf(hv.x, w0, acc[r]);
      acc[r] = fmaf(hv.y, w1, acc[r]);
      acc[r] = fmaf(hv.z, w2, acc[r]);
      acc[r] = fmaf(hv.w, w3, acc[r]);
    }
  }

  const float we = Wm[e * SW + 2 * DD];  // wJ[e]
#pragma unroll
  for (int r = 0; r < 4; ++r) {
    const float sm = wave_reduce_add(acc[r]);
    if (lane == 0) pS[wv][r] = sm;
  }
  {
    const float sw = wave_reduce_add(we);
    if (lane == 0) pw[wv] = sw;
  }
  __syncthreads();

  const int base2 = half * 2;
  const float muw = (pw[0] + pw[1]) * (1.f / DD);
  const float wtil = we - muw;
  float c[4];
#pragma unroll
  for (int r = 0; r < 4; ++r) {
    const float mu = (pS[base2][r] + pS[base2 + 1][r]) * (1.f / DD);
    c[r] = acc[r] - mu;
  }
  float* outp = (half == 0 ? u : s) + (size_t)(b * NN + r0) * DD;
#pragma unroll
  for (int r = 0; r < 4; ++r) outp[r * DD + e] = c[r];

#pragma unroll
  for (int r = 0; r < 4; ++r) {
    const float q = wave_reduce_add(c[r] * c[r]);
    const float dd = wave_reduce_add(c[r] * wtil);
    if (lane == 0) { pQ[wv][r] = q; pD[wv][r] = dd; }
  }
  __syncthreads();
  if (lane < 4 && (wv & 1) == 0) {
    const int r = lane;
    const int row = b * NN + r0 + r;
    if (half == 0) {
      rowA[row]  = pQ[0][r] + pQ[1][r];
      rowD2[row] = 2.f * (pD[0][r] + pD[1][r]);
    } else {
      rowB[row]  = pQ[2][r] + pQ[3][r];
      rowE2[row] = 2.f * (pD[2][r] + pD[3][r]);
    }
  }
}

// ---------------- K2: P = A_i + B_j + 2*dot(u~_i, s~_j)  (32x32 tiles) -----
__global__ __launch_bounds__(256) void k_cross(
    const float* __restrict__ u, const float* __restrict__ s,
    const float* __restrict__ rowA, const float* __restrict__ rowB,
    float* __restrict__ Gp) {
  const int bid = blockIdx.x;            // 512: b*64 + tile
  const int b = bid >> 6;
  const int t = bid & 63;
  const int r0 = (t >> 3) * 32, c0 = (t & 7) * 32;
  const int tid = threadIdx.x;
  const int ty = tid >> 4, tx = tid & 15;

  __shared__ float Us[32][132], Ss[32][132];   // +4 pad: conflict-free rows
  const float* ub = u + (size_t)(b * NN + r0) * DD;
  const float* sb = s + (size_t)(b * NN + c0) * DD;
  {
    const int row = tid >> 5, col = (tid & 31) * 4;
#pragma unroll
    for (int rr = 0; rr < 4; ++rr) {
      const float4 uv = *(const float4*)(ub + (size_t)(row + rr * 8) * DD + col);
      const float4 sv = *(const float4*)(sb + (size_t)(row + rr * 8) * DD + col);
      *(float4*)(&Us[row + rr * 8][col]) = uv;
      *(float4*)(&Ss[row + rr * 8][col]) = sv;
    }
  }
  __syncthreads();

  float a00 = 0, a01 = 0, a10 = 0, a11 = 0;
  for (int k = 0; k < DD; k += 4) {
    const float4 A0 = *(const float4*)(&Us[ty][k]);
    const float4 A1 = *(const float4*)(&Us[ty + 16][k]);
    const float4 B0 = *(const float4*)(&Ss[tx][k]);
    const float4 B1 = *(const float4*)(&Ss[tx + 16][k]);
    a00 = fmaf(A0.x, B0.x, a00); a00 = fmaf(A0.y, B0.y, a00);
    a00 = fmaf(A0.z, B0.z, a00); a00 = fmaf(A0.w, B0.w, a00);
    a01 = fmaf(A0.x, B1.x, a01); a01 = fmaf(A0.y, B1.y, a01);
    a01 = fmaf(A0.z, B1.z, a01); a01 = fmaf(A0.w, B1.w, a01);
    a10 = fmaf(A1.x, B0.x, a10); a10 = fmaf(A1.y, B0.y, a10);
    a10 = fmaf(A1.z, B0.z, a10); a10 = fmaf(A1.w, B0.w, a10);
    a11 = fmaf(A1.x, B1.x, a11); a11 = fmaf(A1.y, B1.y, a11);
    a11 = fmaf(A1.z, B1.z, a11); a11 = fmaf(A1.w, B1.w, a11);
  }
  const float Ar0 = rowA[b * NN + r0 + ty];
  const float Ar1 = rowA[b * NN + r0 + ty + 16];
  const float Bc0 = rowB[b * NN + c0 + tx];
  const float Bc1 = rowB[b * NN + c0 + tx + 16];
  float* gp = Gp + ((size_t)(b * NN + r0 + ty)) * NN + c0;
  gp[tx]                = Ar0 + Bc0 + 2.f * a00;
  gp[tx + 16]           = Ar0 + Bc1 + 2.f * a01;
  gp[16 * NN + tx]      = Ar1 + Bc0 + 2.f * a10;
  gp[16 * NN + tx + 16] = Ar1 + Bc1 + 2.f * a11;
}

// ---------------- K3: fused message LN+SiLU+aggregate (no per-pair reduce) -
__global__ __launch_bounds__(256) void k_msg(
    const float* __restrict__ u, const float* __restrict__ s,
    const float* __restrict__ Gp, const float* __restrict__ rowD2,
    const float* __restrict__ rowE2, const float* __restrict__ adj,
    const float* __restrict__ Wm, const float* __restrict__ g,
    const float* __restrict__ be, float* __restrict__ agg) {
  const int blk = blockIdx.x;            // 2048 = b*256 + i
  const int b = blk >> 8, i = blk & 255;
  const int tid = threadIdx.x, lane = tid & 63, wv = tid >> 6;

  __shared__ float4 s_pak[NN];           // {adj, P, E2, -}
  __shared__ float sacc[4][DD];

  s_pak[tid] = make_float4(adj[(size_t)blk * NN + tid],
                           Gp[(size_t)blk * NN + tid],
                           rowE2[b * NN + tid], 0.f);

  // lane owns elements {2*lane, 2*lane+1}
  const float2 uu = *(const float2*)(u + (size_t)blk * DD + 2 * lane);
  const float w0 = Wm[(2 * lane) * SW + 2 * DD];
  const float w1 = Wm[(2 * lane + 1) * SW + 2 * DD];
  const float2 g2  = *(const float2*)(g + 2 * lane);
  const float2 be2 = *(const float2*)(be + 2 * lane);
  const float muw = wave_reduce_add(w0 + w1) * (1.f / DD);
  const float wt0 = w0 - muw, wt1 = w1 - muw;
  const float C = wave_reduce_add(wt0 * wt0 + wt1 * wt1);
  const float D2i = rowD2[blk];
  __syncthreads();

  float acc0 = 0.f, acc1 = 0.f;
  const float* srow = s + (size_t)b * NN * DD + 2 * lane;
#pragma unroll 2
  for (int j = wv; j < NN; j += 4) {
    if (j == i) continue;                // wave-uniform
    const float4 pk = s_pak[j];
    const float2 ss = *(const float2*)(srow + j * DD);
    const float aJ = pk.x;
    const float q = fmaf(aJ, fmaf(aJ, C, D2i + pk.z), pk.y);
    const float rs = __builtin_amdgcn_rsqf(fmaf(q, 1.f / DD, EPSV));
    const float x0 = fmaf(aJ, wt0, uu.x + ss.x);
    const float x1 = fmaf(aJ, wt1, uu.y + ss.y);
    const float y0 = fmaf(x0 * rs, g2.x, be2.x);
    const float y1 = fmaf(x1 * rs, g2.y, be2.y);
    acc0 = fmaf(y0, __builtin_amdgcn_rcpf(1.f + __expf(-y0)), acc0);
    acc1 = fmaf(y1, __builtin_amdgcn_rcpf(1.f + __expf(-y1)), acc1);
  }
  *(float2*)(&sacc[wv][2 * lane]) = make_float2(acc0, acc1);
  __syncthreads();
  if (tid < DD) {
    agg[(size_t)blk * DD + tid] =
        sacc[0][tid] + sacc[1][tid] + sacc[2][tid] + sacc[3][tid];
  }
}

// ---------------- K4: update GEMM (split-K) + LN + SiLU + residual ---------
__global__ __launch_bounds__(256) void k_upd(
    const float* __restrict__ h, const float* __restrict__ agg,
    const float* __restrict__ WuT, const float* __restrict__ bu,
    const float* __restrict__ gu, const float* __restrict__ beu,
    float* __restrict__ out) {
  const int blk = blockIdx.x;            // 512 blocks, 4 rows each
  const int b = blk >> 6;
  const int r0 = (blk & 63) * 4;
  const int tid = threadIdx.x;
  const int half = tid >> 7, e = tid & 127;
  const int wv = tid >> 6, lane = tid & 63;

  __shared__ float hs[4][DD], ags[4][DD], comb[4][DD];
  __shared__ float pm[2][4], pq[2][4];
  const size_t base = (size_t)(b * NN + r0) * DD;
  if (tid < DD) {
#pragma unroll
    for (int r = 0; r < 4; ++r) hs[r][e] = h[base + r * DD + e];
  } else {
#pragma unroll
    for (int r = 0; r < 4; ++r) ags[r][e] = agg[base + r * DD + e];
  }
  __syncthreads();

  float acc[4];
  const float bias = (half == 0) ? bu[e] : 0.f;
#pragma unroll
  for (int r = 0; r < 4; ++r) acc[r] = bias;

  const float* wt = WuT + (size_t)half * DD * DD + e;
  const float(*inp)[DD] = (half == 0) ? hs : ags;
  for (int k = 0; k < DD; k += 4) {
    const float w0 = wt[(k + 0) * DD], w1 = wt[(k + 1) * DD];
    const float w2 = wt[(k + 2) * DD], w3 = wt[(k + 3) * DD];
#pragma unroll
    for (int r = 0; r < 4; ++r) {
      const float4 hv = *(const float4*)(&inp[r][k]);
      acc[r] = fmaf(hv.x, w0, acc[r]);
      acc[r] = fmaf(hv.y, w1, acc[r]);
      acc[r] = fmaf(hv.z, w2, acc[r]);
      acc[r] = fmaf(hv.w, w3, acc[r]);
    }
  }
  if (half == 1) {
#pragma unroll
    for (int r = 0; r < 4; ++r) comb[r][e] = acc[r];
  }
  __syncthreads();
  float v[4];
  if (half == 0) {
#pragma unroll
    for (int r = 0; r < 4; ++r) {
      v[r] = acc[r] + comb[r][e];
      const float sm = wave_reduce_add(v[r]);
      const float sq = wave_reduce_add(v[r] * v[r]);
      if (lane == 0) { pm[wv][r] = sm; pq[wv][r] = sq; }
    }
  }
  __syncthreads();
  if (half == 0) {
    const float ge = gu[e], bee = beu[e];
#pragma unroll
    for (int r = 0; r < 4; ++r) {
      const float mean = (pm[0][r] + pm[1][r]) * (1.f / DD);
      const float var = (pq[0][r] + pq[1][r]) * (1.f / DD) - mean * mean;
      const float rs = __builtin_amdgcn_rsqf(var + EPSV);
      const float y = fmaf((v[r] - mean) * rs, ge, bee);
      const float sg = __builtin_amdgcn_rcpf(1.f + __expf(-y));
      out[base + r * DD + e] = hs[r][e] + y * sg;
    }
  }
}

extern "C" void kernel_launch(void* const* d_in, const int* in_sizes, int n_in,
                              void* d_out, int out_size, void* d_ws, size_t ws_size,
                              hipStream_t stream) {
  const float* h    = (const float*)d_in[0];
  const float* adj  = (const float*)d_in[1];
  const float* Wm   = (const float*)d_in[2];
  const float* bmsg = (const float*)d_in[3];
  const float* gmsg = (const float*)d_in[4];
  const float* bemsg= (const float*)d_in[5];
  const float* Wu   = (const float*)d_in[6];
  const float* bupd = (const float*)d_in[7];
  const float* gupd = (const float*)d_in[8];
  const float* beupd= (const float*)d_in[9];
  float* out = (float*)d_out;

  float* ws    = (float*)d_ws;
  float* u     = ws;                        // 262144
  float* s     = u + BB * NN * DD;          // 262144
  float* aggp  = s + BB * NN * DD;          // 262144
  float* Gp    = aggp + BB * NN * DD;       // 524288
  float* rowA  = Gp + BB * NN * NN;         // 2048
  float* rowB  = rowA + BB * NN;            // 2048
  float* rowD2 = rowB + BB * NN;            // 2048
  float* rowE2 = rowD2 + BB * NN;           // 2048
  float* WmT   = rowE2 + BB * NN;           // 32768
  float* WuT   = WmT + 2 * DD * DD;         // 32768

  k_wt<<<128, 512, 0, stream>>>(Wm, Wu, WmT, WuT);
  k_proj<<<512, 256, 0, stream>>>(h, WmT, Wm, bmsg, u, s, rowA, rowB, rowD2, rowE2);
  k_cross<<<512, 256, 0, stream>>>(u, s, rowA, rowB, Gp);
  k_msg<<<2048, 256, 0, stream>>>(u, s, Gp, rowD2, rowE2, adj, Wm, gmsg, bemsg, aggp);
  k_upd<<<512, 256, 0, stream>>>(h, aggp, WuT, bupd, gupd, beupd, out);
}

// Round 6
// 65.456 us; speedup vs baseline: 1.2245x; 1.2245x over previous
//
#include <hip/hip_runtime.h>

#define BB 8
#define NN 256
#define DD 128
#define SW 257  // W_msg row stride (2D+1)
#define SU 256  // W_upd row stride (2D)
#define EPSV 1e-5f

__device__ __forceinline__ float wave_reduce_add(float v) {
#pragma unroll
  for (int off = 32; off > 0; off >>= 1) v += __shfl_xor(v, off, 64);
  return v;
}

// ---------------- K1: centered u,s + per-row LN scalars + wtilde -----------
// 256 threads: half 0 -> u (Wt), half 1 -> s (Ws). 4 rows/block.
// W rows read contiguous per-thread (L2-resident gather) -- no transpose pass.
__global__ __launch_bounds__(256) void k_proj(
    const float* __restrict__ h, const float* __restrict__ Wm,
    const float* __restrict__ bmsg,
    float* __restrict__ u, float* __restrict__ s,
    float* __restrict__ rowA, float* __restrict__ rowB,
    float* __restrict__ rowD2, float* __restrict__ rowE2,
    float* __restrict__ wtilv) {
  const int blk = blockIdx.x;            // 512: 64 per batch, 4 rows each
  const int b = blk >> 6;
  const int r0 = (blk & 63) * 4;
  const int tid = threadIdx.x;
  const int half = tid >> 7, e = tid & 127;
  const int wv = tid >> 6, lane = tid & 63;

  __shared__ float hs[4][DD];
  __shared__ float pS[4][4], pw[2], pQ[4][4], pD[4][4];

  const float* hb = h + (size_t)(b * NN + r0) * DD;
  if (tid < DD) {
#pragma unroll
    for (int r = 0; r < 4; ++r) hs[r][e] = hb[r * DD + e];
  }
  __syncthreads();

  float acc[4];
  const float bm = (half == 0) ? bmsg[e] : 0.f;   // fold b_msg into u
#pragma unroll
  for (int r = 0; r < 4; ++r) acc[r] = bm;

  const float* wr = Wm + (size_t)e * SW + half * DD;
#pragma unroll 8
  for (int k = 0; k < DD; k += 4) {
    const float4 w4 = *(const float4*)(wr + k);
#pragma unroll
    for (int r = 0; r < 4; ++r) {
      const float4 hv = *(const float4*)(&hs[r][k]);
      acc[r] = fmaf(hv.x, w4.x, acc[r]);
      acc[r] = fmaf(hv.y, w4.y, acc[r]);
      acc[r] = fmaf(hv.z, w4.z, acc[r]);
      acc[r] = fmaf(hv.w, w4.w, acc[r]);
    }
  }

  const float we = Wm[(size_t)e * SW + 2 * DD];   // wJ[e]
#pragma unroll
  for (int r = 0; r < 4; ++r) {
    const float sm = wave_reduce_add(acc[r]);
    if (lane == 0) pS[wv][r] = sm;
  }
  {
    const float sw = wave_reduce_add(we);
    if (lane == 0 && wv < 2) pw[wv] = sw;         // half-0 waves cover e=0..127
  }
  __syncthreads();

  const int b2 = half * 2;
  const float muw = (pw[0] + pw[1]) * (1.f / DD);
  const float wtil = we - muw;
  float c[4];
#pragma unroll
  for (int r = 0; r < 4; ++r)
    c[r] = acc[r] - (pS[b2][r] + pS[b2 + 1][r]) * (1.f / DD);

  float* outp = (half == 0 ? u : s) + (size_t)(b * NN + r0) * DD;
#pragma unroll
  for (int r = 0; r < 4; ++r) outp[r * DD + e] = c[r];
  if (blk == 0 && half == 0) wtilv[e] = wtil;     // shared by all k_msg blocks

#pragma unroll
  for (int r = 0; r < 4; ++r) {
    const float q = wave_reduce_add(c[r] * c[r]);
    const float dd = wave_reduce_add(c[r] * wtil);
    if (lane == 0) { pQ[wv][r] = q; pD[wv][r] = dd; }
  }
  __syncthreads();
  if (tid < 4) {
    const int row = b * NN + r0 + tid;
    rowA[row]  = pQ[0][tid] + pQ[1][tid];
    rowD2[row] = 2.f * (pD[0][tid] + pD[1][tid]);
    rowB[row]  = pQ[2][tid] + pQ[3][tid];
    rowE2[row] = 2.f * (pD[2][tid] + pD[3][tid]);
  }
}

// ---------------- K2: P = A_i + B_j + 2*dot(u~_i, s~_j)  (32x32 tiles) -----
__global__ __launch_bounds__(256) void k_cross(
    const float* __restrict__ u, const float* __restrict__ s,
    const float* __restrict__ rowA, const float* __restrict__ rowB,
    float* __restrict__ Gp) {
  const int bid = blockIdx.x;            // 512: b*64 + tile
  const int b = bid >> 6;
  const int t = bid & 63;
  const int r0 = (t >> 3) * 32, c0 = (t & 7) * 32;
  const int tid = threadIdx.x;
  const int ty = tid >> 4, tx = tid & 15;

  __shared__ float Us[32][132], Ss[32][132];
  const float* ub = u + (size_t)(b * NN + r0) * DD;
  const float* sb = s + (size_t)(b * NN + c0) * DD;
  {
    const int row = tid >> 5, col = (tid & 31) * 4;
#pragma unroll
    for (int rr = 0; rr < 4; ++rr) {
      const float4 uv = *(const float4*)(ub + (size_t)(row + rr * 8) * DD + col);
      const float4 sv = *(const float4*)(sb + (size_t)(row + rr * 8) * DD + col);
      *(float4*)(&Us[row + rr * 8][col]) = uv;
      *(float4*)(&Ss[row + rr * 8][col]) = sv;
    }
  }
  __syncthreads();

  float a00 = 0, a01 = 0, a10 = 0, a11 = 0;
  for (int k = 0; k < DD; k += 4) {
    const float4 A0 = *(const float4*)(&Us[ty][k]);
    const float4 A1 = *(const float4*)(&Us[ty + 16][k]);
    const float4 B0 = *(const float4*)(&Ss[tx][k]);
    const float4 B1 = *(const float4*)(&Ss[tx + 16][k]);
    a00 = fmaf(A0.x, B0.x, a00); a00 = fmaf(A0.y, B0.y, a00);
    a00 = fmaf(A0.z, B0.z, a00); a00 = fmaf(A0.w, B0.w, a00);
    a01 = fmaf(A0.x, B1.x, a01); a01 = fmaf(A0.y, B1.y, a01);
    a01 = fmaf(A0.z, B1.z, a01); a01 = fmaf(A0.w, B1.w, a01);
    a10 = fmaf(A1.x, B0.x, a10); a10 = fmaf(A1.y, B0.y, a10);
    a10 = fmaf(A1.z, B0.z, a10); a10 = fmaf(A1.w, B0.w, a10);
    a11 = fmaf(A1.x, B1.x, a11); a11 = fmaf(A1.y, B1.y, a11);
    a11 = fmaf(A1.z, B1.z, a11); a11 = fmaf(A1.w, B1.w, a11);
  }
  const float Ar0 = rowA[b * NN + r0 + ty];
  const float Ar1 = rowA[b * NN + r0 + ty + 16];
  const float Bc0 = rowB[b * NN + c0 + tx];
  const float Bc1 = rowB[b * NN + c0 + tx + 16];
  float* gp = Gp + ((size_t)(b * NN + r0 + ty)) * NN + c0;
  gp[tx]                = Ar0 + Bc0 + 2.f * a00;
  gp[tx + 16]           = Ar0 + Bc1 + 2.f * a01;
  gp[16 * NN + tx]      = Ar1 + Bc0 + 2.f * a10;
  gp[16 * NN + tx + 16] = Ar1 + Bc1 + 2.f * a11;
}

// ---------------- K3: fused message LN+SiLU+aggregate ----------------------
__global__ __launch_bounds__(256) void k_msg(
    const float* __restrict__ u, const float* __restrict__ s,
    const float* __restrict__ Gp, const float* __restrict__ rowD2,
    const float* __restrict__ rowE2, const float* __restrict__ adj,
    const float* __restrict__ wtilv, const float* __restrict__ g,
    const float* __restrict__ be, float* __restrict__ agg) {
  const int blk = blockIdx.x;            // 2048 = b*256 + i
  const int b = blk >> 8, i = blk & 255;
  const int tid = threadIdx.x, lane = tid & 63, wv = tid >> 6;

  __shared__ float4 s_pak[NN];           // {adj, P, E2, -}
  __shared__ float sacc[4][DD];

  s_pak[tid] = make_float4(adj[(size_t)blk * NN + tid],
                           Gp[(size_t)blk * NN + tid],
                           rowE2[b * NN + tid], 0.f);

  const float2 uu  = *(const float2*)(u + (size_t)blk * DD + 2 * lane);
  const float2 wt2 = *(const float2*)(wtilv + 2 * lane);
  const float2 g2  = *(const float2*)(g + 2 * lane);
  const float2 be2 = *(const float2*)(be + 2 * lane);
  const float C = wave_reduce_add(fmaf(wt2.x, wt2.x, wt2.y * wt2.y));
  const float D2i = rowD2[blk];
  __syncthreads();

  float acc0 = 0.f, acc1 = 0.f;
  const float* srow = s + (size_t)b * NN * DD + 2 * lane;
#pragma unroll 4
  for (int j = wv; j < NN; j += 4) {
    if (j == i) continue;                // wave-uniform
    const float4 pk = s_pak[j];
    const float2 ss = *(const float2*)(srow + (size_t)j * DD);
    const float aJ = pk.x;
    const float q = fmaf(aJ, fmaf(aJ, C, D2i + pk.z), pk.y);
    const float rs = __builtin_amdgcn_rsqf(fmaf(q, 1.f / DD, EPSV));
    const float x0 = fmaf(aJ, wt2.x, uu.x + ss.x);
    const float x1 = fmaf(aJ, wt2.y, uu.y + ss.y);
    const float y0 = fmaf(x0 * rs, g2.x, be2.x);
    const float y1 = fmaf(x1 * rs, g2.y, be2.y);
    acc0 = fmaf(y0, __builtin_amdgcn_rcpf(1.f + __expf(-y0)), acc0);
    acc1 = fmaf(y1, __builtin_amdgcn_rcpf(1.f + __expf(-y1)), acc1);
  }
  *(float2*)(&sacc[wv][2 * lane]) = make_float2(acc0, acc1);
  __syncthreads();
  if (tid < DD) {
    agg[(size_t)blk * DD + tid] =
        sacc[0][tid] + sacc[1][tid] + sacc[2][tid] + sacc[3][tid];
  }
}

// ---------------- K4: update GEMM (split-K) + LN + SiLU + residual ---------
__global__ __launch_bounds__(256) void k_upd(
    const float* __restrict__ h, const float* __restrict__ agg,
    const float* __restrict__ Wu, const float* __restrict__ bu,
    const float* __restrict__ gu, const float* __restrict__ beu,
    float* __restrict__ out) {
  const int blk = blockIdx.x;            // 512 blocks, 4 rows each
  const int b = blk >> 6;
  const int r0 = (blk & 63) * 4;
  const int tid = threadIdx.x;
  const int half = tid >> 7, e = tid & 127;
  const int wv = tid >> 6, lane = tid & 63;

  __shared__ float hs[4][DD], ags[4][DD], comb[4][DD];
  __shared__ float pm[2][4], pq[2][4];
  const size_t base = (size_t)(b * NN + r0) * DD;
  if (tid < DD) {
#pragma unroll
    for (int r = 0; r < 4; ++r) hs[r][e] = h[base + r * DD + e];
  } else {
#pragma unroll
    for (int r = 0; r < 4; ++r) ags[r][e] = agg[base + r * DD + e];
  }
  __syncthreads();

  float acc[4];
  const float bias = (half == 0) ? bu[e] : 0.f;
#pragma unroll
  for (int r = 0; r < 4; ++r) acc[r] = bias;

  const float* wr = Wu + (size_t)e * SU + half * DD;
  const float(*inp)[DD] = (half == 0) ? hs : ags;
#pragma unroll 8
  for (int k = 0; k < DD; k += 4) {
    const float4 w4 = *(const float4*)(wr + k);
#pragma unroll
    for (int r = 0; r < 4; ++r) {
      const float4 hv = *(const float4*)(&inp[r][k]);
      acc[r] = fmaf(hv.x, w4.x, acc[r]);
      acc[r] = fmaf(hv.y, w4.y, acc[r]);
      acc[r] = fmaf(hv.z, w4.z, acc[r]);
      acc[r] = fmaf(hv.w, w4.w, acc[r]);
    }
  }
  if (half == 1) {
#pragma unroll
    for (int r = 0; r < 4; ++r) comb[r][e] = acc[r];
  }
  __syncthreads();
  float v[4];
  if (half == 0) {
#pragma unroll
    for (int r = 0; r < 4; ++r) {
      v[r] = acc[r] + comb[r][e];
      const float sm = wave_reduce_add(v[r]);
      const float sq = wave_reduce_add(v[r] * v[r]);
      if (lane == 0) { pm[wv][r] = sm; pq[wv][r] = sq; }
    }
  }
  __syncthreads();
  if (half == 0) {
    const float ge = gu[e], bee = beu[e];
#pragma unroll
    for (int r = 0; r < 4; ++r) {
      const float mean = (pm[0][r] + pm[1][r]) * (1.f / DD);
      const float var = (pq[0][r] + pq[1][r]) * (1.f / DD) - mean * mean;
      const float rs = __builtin_amdgcn_rsqf(var + EPSV);
      const float y = fmaf((v[r] - mean) * rs, ge, bee);
      const float sg = __builtin_amdgcn_rcpf(1.f + __expf(-y));
      out[base + r * DD + e] = hs[r][e] + y * sg;
    }
  }
}

extern "C" void kernel_launch(void* const* d_in, const int* in_sizes, int n_in,
                              void* d_out, int out_size, void* d_ws, size_t ws_size,
                              hipStream_t stream) {
  const float* h    = (const float*)d_in[0];
  const float* adj  = (const float*)d_in[1];
  const float* Wm   = (const float*)d_in[2];
  const float* bmsg = (const float*)d_in[3];
  const float* gmsg = (const float*)d_in[4];
  const float* bemsg= (const float*)d_in[5];
  const float* Wu   = (const float*)d_in[6];
  const float* bupd = (const float*)d_in[7];
  const float* gupd = (const float*)d_in[8];
  const float* beupd= (const float*)d_in[9];
  float* out = (float*)d_out;

  float* ws    = (float*)d_ws;
  float* u     = ws;                        // 262144
  float* s     = u + BB * NN * DD;          // 262144
  float* aggp  = s + BB * NN * DD;          // 262144
  float* Gp    = aggp + BB * NN * DD;       // 524288
  float* rowA  = Gp + BB * NN * NN;         // 2048
  float* rowB  = rowA + BB * NN;            // 2048
  float* rowD2 = rowB + BB * NN;            // 2048
  float* rowE2 = rowD2 + BB * NN;           // 2048
  float* wtilv = rowE2 + BB * NN;           // 128

  k_proj<<<512, 256, 0, stream>>>(h, Wm, bmsg, u, s, rowA, rowB, rowD2, rowE2, wtilv);
  k_cross<<<512, 256, 0, stream>>>(u, s, rowA, rowB, Gp);
  k_msg<<<2048, 256, 0, stream>>>(u, s, Gp, rowD2, rowE2, adj, wtilv, gmsg, bemsg, aggp);
  k_upd<<<512, 256, 0, stream>>>(h, aggp, Wu, bupd, gupd, beupd, out);
}